// Round 1
// baseline (269.939 us; speedup 1.0000x reference)
//
#include <hip/hip_runtime.h>

#define N_RAYS 65536
#define N_SAMPLES 128

__device__ __forceinline__ float sigmoidf(float x) {
    return 1.0f / (1.0f + __expf(-x));
}

__global__ __launch_bounds__(256) void neus_kernel(
    const float* __restrict__ sdf,
    const float* __restrict__ color,
    const float* __restrict__ z_vals,
    const float* __restrict__ grad_theta,
    const float* __restrict__ rays_d,
    const float* __restrict__ s_ptr,
    const float* __restrict__ car_ptr,
    float* __restrict__ out_pixel,     // [N,3]
    float* __restrict__ out_invdepth,  // [N]
    float* __restrict__ out_weight)    // [N,S]
{
    const int lane = threadIdx.x & 63;
    const int wave = threadIdx.x >> 6;
    const int ray  = blockIdx.x * 4 + wave;

    const float sv  = s_ptr[0];
    const float car = car_ptr[0];

    const float rdx = rays_d[ray * 3 + 0];
    const float rdy = rays_d[ray * 3 + 1];
    const float rdz = rays_d[ray * 3 + 2];

    const int s0   = 2 * lane;            // first sample owned by this lane
    const int base = ray * N_SAMPLES;

    // Coalesced vector loads: lane i owns samples 2i, 2i+1
    const float2 sd  = *(const float2*)(sdf    + base + s0);
    const float2 zz  = *(const float2*)(z_vals + base + s0);
    const float2 c01 = *(const float2*)(color      + (size_t)base * 3 + 6 * lane);
    const float2 c23 = *(const float2*)(color      + (size_t)base * 3 + 6 * lane + 2);
    const float2 c45 = *(const float2*)(color      + (size_t)base * 3 + 6 * lane + 4);
    const float2 g01 = *(const float2*)(grad_theta + (size_t)base * 3 + 6 * lane);
    const float2 g23 = *(const float2*)(grad_theta + (size_t)base * 3 + 6 * lane + 2);
    const float2 g45 = *(const float2*)(grad_theta + (size_t)base * 3 + 6 * lane + 4);

    // z[2*lane+2] comes from neighbor lane's first z (garbage at lane 63; unused there)
    const float z_next = __shfl_down(zz.x, 1, 64);

    // true cosine for both samples
    const float tcA = rdx * g01.x + rdy * g01.y + rdz * g23.x;   // sample 2i
    const float tcB = rdx * g23.y + rdy * g45.x + rdz * g45.y;   // sample 2i+1

    const float one_m_car = 1.0f - car;
    auto iter_cos = [&](float tc) -> float {
        float a = fmaxf(-tc * 0.5f + 0.5f, 0.0f);
        float b = fmaxf(-tc, 0.0f);
        return -(a * one_m_car + b * car);
    };
    const float icA = iter_cos(tcA);
    const float icB = iter_cos(tcB);

    const float dA = zz.y - zz.x;       // dists[2i]   (2i   <= 126 always)
    const float dB = z_next - zz.y;     // dists[2i+1] (invalid at lane 63 -> alpha forced 0)

    auto alpha_f = [&](float sdv, float ic, float d) -> float {
        float h  = ic * d * 0.5f;
        float pc = sigmoidf((sdv - h) * sv);   // prev_cdf
        float nc = sigmoidf((sdv + h) * sv);   // next_cdf
        float a  = (pc - nc + 1e-5f) / (pc + 1e-5f);
        return fminf(fmaxf(a, 0.0f), 1.0f);
    };

    const float alphaA = alpha_f(sd.x, icA, dA);
    const float alphaB = (lane == 63) ? 0.0f : alpha_f(sd.y, icB, dB);

    const float omA = 1.0f - alphaA;
    const float omB = 1.0f - alphaB;

    // Wave-wide exclusive product scan of (omA*omB)
    float scan = omA * omB;
    #pragma unroll
    for (int off = 1; off < 64; off <<= 1) {
        float v = __shfl_up(scan, off, 64);
        if (lane >= off) scan *= v;
    }
    float excl = __shfl_up(scan, 1, 64);
    if (lane == 0) excl = 1.0f;

    // T[2i] = prod_{j<2i}(1-alpha_j), T[2i+1] = T[2i]*(1-alpha_{2i})
    const float TA = excl;
    const float TB = excl * omA;

    // Faithful to ref: transmittance[0] is a prepended ZERO -> weight[0]=0
    const float wA = (lane == 0) ? 0.0f : TA * alphaA;
    const float wB = TB * alphaB;   // lane 63: alphaB==0 -> 0

    // Per-lane partial sums for pixel & invdepth
    float pr  = wA * c01.x + wB * c23.y;
    float pg  = wA * c01.y + wB * c45.x;
    float pb  = wA * c23.x + wB * c45.y;
    float inv = wA / zz.x + wB / zz.y;

    // Butterfly reduction across the 64-lane wave
    #pragma unroll
    for (int off = 32; off > 0; off >>= 1) {
        pr  += __shfl_xor(pr,  off, 64);
        pg  += __shfl_xor(pg,  off, 64);
        pb  += __shfl_xor(pb,  off, 64);
        inv += __shfl_xor(inv, off, 64);
    }

    // Coalesced weight store
    *(float2*)(out_weight + base + s0) = make_float2(wA, wB);

    if (lane == 0) {
        out_pixel[ray * 3 + 0] = pr;
        out_pixel[ray * 3 + 1] = pg;
        out_pixel[ray * 3 + 2] = pb;
        out_invdepth[ray]      = inv;
    }
}

extern "C" void kernel_launch(void* const* d_in, const int* in_sizes, int n_in,
                              void* d_out, int out_size, void* d_ws, size_t ws_size,
                              hipStream_t stream) {
    const float* sdf        = (const float*)d_in[0];
    const float* color      = (const float*)d_in[1];
    const float* z_vals     = (const float*)d_in[2];
    const float* grad_theta = (const float*)d_in[3];
    const float* rays_d     = (const float*)d_in[4];
    const float* s_ptr      = (const float*)d_in[5];
    const float* car_ptr    = (const float*)d_in[6];

    float* out          = (float*)d_out;
    float* out_pixel    = out;                        // N*3
    float* out_invdepth = out + (size_t)N_RAYS * 3;   // N
    float* out_weight   = out + (size_t)N_RAYS * 4;   // N*S

    dim3 block(256);                 // 4 waves = 4 rays per block
    dim3 grid(N_RAYS / 4);           // 16384 blocks

    neus_kernel<<<grid, block, 0, stream>>>(
        sdf, color, z_vals, grad_theta, rays_d, s_ptr, car_ptr,
        out_pixel, out_invdepth, out_weight);
}